// Round 10
// baseline (128.596 us; speedup 1.0000x reference)
//
#include <hip/hip_runtime.h>

#define VOCAB 50257

typedef __attribute__((ext_vector_type(4))) float floatx4;
typedef __attribute__((ext_vector_type(4))) int intx4;
typedef __attribute__((ext_vector_type(8))) int int8v;

// identity E8M0 scales (2^0) in every byte -> opsel-proof
#define SC1 0x7F7F7F7F
#define MFMA_F4F8(a, b, c) \
  __builtin_amdgcn_mfma_scale_f32_16x16x128_f8f6f4((a), (b), (c), 4, 0, 0, SC1, 0, SC1)

// fp4 e2m1 quantizer (RNE-ish to grid {0,.5,1,1.5,2,3,4,6}), x256
static __device__ __forceinline__ unsigned fp4q(float v) {
  float a = fabsf(v) * 256.f;
  unsigned s = (v < 0.f) ? 8u : 0u;
  unsigned c;
  if (a < 0.25f) c = 0;
  else if (a < 0.75f) c = 1;
  else if (a < 1.25f) c = 2;
  else if (a < 1.75f) c = 3;
  else if (a < 2.5f)  c = 4;
  else if (a < 3.5f)  c = 5;
  else if (a < 5.0f)  c = 6;
  else c = 7;
  return s | c;
}

// ---------------------------------------------------------------------------
// Weight pre-shuffle: fp32 -> fp4 (x256), frag-major for K=128 scaled MFMA.
// A-frag: A[m = lane&15][k = 32*(lane>>4) + 8*r + j], r = dword 0..3, j = nibble.
// W1f dword ((p*64+lane)*4+r): W1[d][16p+(l&15)][32(l>>4)+8r+j]   (p = 2*w2+mt)
// W2f: W2[d][16*(p>>1)+(l&15)][128*(p&1)+32(l>>4)+8r+j]           (p = 2*w2+kh)
// ---------------------------------------------------------------------------
__global__ void prep_weights(const float* __restrict__ W1, const float* __restrict__ W2,
                             unsigned* __restrict__ W1f, unsigned* __restrict__ W2f) {
  int g = blockIdx.x * 256 + threadIdx.x;   // 0..131071
  int arr = g >> 16;
  int s = g & 65535;
  int d = s >> 12;
  int gg = s & 4095;         // dword within domain
  int p = gg >> 8;           // 0..15
  int lane = (gg >> 2) & 63;
  int r = gg & 3;
  int lm = lane & 15, lq = lane >> 4;
  const float* src;
  unsigned* dst;
  if (arr == 0) {
    src = W1 + (size_t)(d * 256 + 16 * p + lm) * 128 + 32 * lq + 8 * r;
    dst = W1f + (size_t)d * 4096 + gg;
  } else {
    src = W2 + (size_t)(d * 128 + 16 * (p >> 1) + lm) * 256 + 128 * (p & 1) + 32 * lq + 8 * r;
    dst = W2f + (size_t)d * 4096 + gg;
  }
  unsigned pk = 0;
#pragma unroll
  for (int j = 0; j < 8; ++j) pk |= fp4q(src[j]) << (4 * j);
  *dst = pk;
}

static __device__ __forceinline__ int pack_fp8(float a, float b, float c, float d) {
  int v = __builtin_amdgcn_cvt_pk_fp8_f32(a, b, 0, false);
  return __builtin_amdgcn_cvt_pk_fp8_f32(c, d, v, true);
}

// ---------------------------------------------------------------------------
// Block = 8 waves (512 thr), 32 tokens; grid 1024 -> 4 blocks/CU = 32 waves/CU.
// GEMM1 m-split 8-way (wave w2 -> mid[32w2..32w2+32), acc[2][2]);
// GEMM2 e-split 8-way (wave w2 -> h[16w2..16w2+16), hm[2], K=256 = 2 mfma/nt).
// Same numerics as R9: fp4 weights x256 (identity MX scales), fp8 act (h x8),
// h master fp32 x131072 (MFMA C operand), mid = mask*acc*(k0+k1*acc).
// LDS 16.6KB, XOR-16B-unit swizzle, domain-invariant addresses, weight prefetch.
// ---------------------------------------------------------------------------
__launch_bounds__(512, 8)
__global__ void domain_chain(const int* __restrict__ x,
                             const float* __restrict__ base_embed,
                             const int* __restrict__ membership,
                             const unsigned char* __restrict__ W1f,
                             const unsigned char* __restrict__ W2f,
                             float* __restrict__ out) {
  __shared__ __align__(16) unsigned char act[16384];
  __shared__ int xs[32];
  __shared__ int mws[32];

  const int tid = threadIdx.x;       // 0..511
  const int w2 = tid >> 6;           // wave 0..7
  const int lane = tid & 63;
  const int lm = lane & 15, lq = lane >> 4;
  const int key = lm & 7;
  const int tokbase = blockIdx.x * 32;

  if (tid < 32) xs[tid] = x[tokbase + tid];
  __syncthreads();
  if (tid >= 32 && tid < 64) {
    int t = tid - 32;
    int tok = xs[t];
    int mw = 0;
#pragma unroll
    for (int d = 0; d < 16; ++d)
      mw |= (membership[d * VOCAB + tok] != 0 ? 1 : 0) << d;
    mws[t] = mw;
  }
  // stage h0 fp32 (32 tok x 128 f32 = 16 KB), float4 units swizzled ^(t&7)
  float4* stag4 = (float4*)act;
#pragma unroll
  for (int i = 0; i < 2; ++i) {
    int idx = tid + i * 512;         // 0..1023
    int t = idx >> 5, c4 = idx & 31;
    stag4[t * 32 + (c4 ^ (t & 7))] = ((const float4*)base_embed)[(size_t)xs[t] * 32 + c4];
  }
  __syncthreads();

  // h master fp32 x131072 (e-slice 16, MFMA C-layout): hm[nt] reg r =
  //   131072 * h[e = 16w2+4lq+r][tok = 16nt+lm]
  floatx4 hm[2];
  int mwr[2];
#pragma unroll
  for (int nt = 0; nt < 2; ++nt) mwr[nt] = mws[nt * 16 + lm];
#pragma unroll
  for (int nt = 0; nt < 2; ++nt) {
    float4 v = stag4[(nt * 16 + lm) * 32 + ((4 * w2 + lq) ^ key)];
    hm[nt] = (floatx4){v.x * 131072.f, v.y * 131072.f, v.z * 131072.f, v.w * 131072.f};
  }

  // domain-invariant LDS byte addresses (unit16 XOR-swizzled by key)
  int hrd[2][2], mrd[2][2][2], mwu[2], hwu, mrow[2], hrow[2];
#pragma unroll
  for (int nt = 0; nt < 2; ++nt) {
    mrow[nt] = (nt * 16 + lm) * 256;           // mid rows: 256B
    hrow[nt] = 8192 + (nt * 16 + lm) * 128;    // h rows: 128B
#pragma unroll
    for (int u = 0; u < 2; ++u)
      hrd[nt][u] = hrow[nt] + (((2 * lq + u) ^ key) << 4);
#pragma unroll
    for (int kh = 0; kh < 2; ++kh)
#pragma unroll
      for (int u = 0; u < 2; ++u)
        mrd[nt][kh][u] = mrow[nt] + ((8 * kh + ((2 * lq + u) ^ key)) << 4);
  }
#pragma unroll
  for (int mt = 0; mt < 2; ++mt) mwu[mt] = (((2 * w2 + mt) ^ key) << 4) + 4 * lq;
  hwu = ((w2 ^ key) << 4) + 4 * lq;

  __syncthreads();   // stag reads done; act reused as mid/h

  // publish initial h fp8 (x8 = hm * 2^-14)
#pragma unroll
  for (int nt = 0; nt < 2; ++nt)
    *(int*)(act + hrow[nt] + hwu) =
        pack_fp8(hm[nt][0] * 6.1035156e-5f, hm[nt][1] * 6.1035156e-5f,
                 hm[nt][2] * 6.1035156e-5f, hm[nt][3] * 6.1035156e-5f);
  __syncthreads();

  const floatx4 vz = {0.f, 0.f, 0.f, 0.f};
  const intx4 z4 = 0;
  const size_t laneoff = (size_t)w2 * 2048 + (size_t)lane * 16;

  // prologue: prefetch d=0 W1 b128 frags (mt 0..1)
  intx4 aw[2];
  {
    const unsigned char* w1d = W1f + laneoff;
#pragma unroll
    for (int mt = 0; mt < 2; ++mt)
      aw[mt] = *(const intx4*)(w1d + mt * 1024);
  }

#pragma unroll 1
  for (int d = 0; d < 16; ++d) {
    // prefetch this domain's W2 frags (kh 0..1)
    intx4 bw[2];
    {
      const unsigned char* w2d = W2f + ((size_t)d << 14) + laneoff;
#pragma unroll
      for (int kh = 0; kh < 2; ++kh)
        bw[kh] = *(const intx4*)(w2d + kh * 1024);
    }

    // ---- phase A: GEMM1 (m=32 slice, n=32 tokens, K=128 in ONE mfma)
    int8v hb[2];
#pragma unroll
    for (int nt = 0; nt < 2; ++nt) {
      intx4 p0 = *(const intx4*)(act + hrd[nt][0]);
      intx4 p1 = *(const intx4*)(act + hrd[nt][1]);
      hb[nt] = __builtin_shufflevector(p0, p1, 0, 1, 2, 3, 4, 5, 6, 7);
    }
    floatx4 acc[2][2];
#pragma unroll
    for (int mt = 0; mt < 2; ++mt) {
      int8v a = __builtin_shufflevector(aw[mt], z4, 0, 1, 2, 3, 4, 5, 6, 7);
#pragma unroll
      for (int nt = 0; nt < 2; ++nt)
        acc[mt][nt] = MFMA_F4F8(a, hb[nt], vz);
    }
    // mid_stored = mask * acc*(k0 + k1*acc)   [= 512*0.1*gelu(acc/2048)]
#pragma unroll
    for (int nt = 0; nt < 2; ++nt) {
      float on = ((mwr[nt] >> d) & 1) ? 1.f : 0.f;
      float k0 = 0.0125f * on, k1 = 4.87035e-6f * on;
#pragma unroll
      for (int mt = 0; mt < 2; ++mt) {
        floatx4 a = acc[mt][nt];
        *(int*)(act + mrow[nt] + mwu[mt]) =
            pack_fp8(a[0] * (k0 + k1 * a[0]), a[1] * (k0 + k1 * a[1]),
                     a[2] * (k0 + k1 * a[2]), a[3] * (k0 + k1 * a[3]));
      }
    }
    __syncthreads();   // mid visible; all phase-A h reads done

    // ---- phase B: GEMM2 (m=16 e-slice, n=32 tokens, K=256 = 2 mfma/nt)
    // prefetch next domain's W1 (aw dead)
    {
      const unsigned char* w1n = W1f + ((size_t)(d + 1) << 14) + laneoff;
#pragma unroll
      for (int mt = 0; mt < 2; ++mt)
        aw[mt] = *(const intx4*)(w1n + mt * 1024);
    }
#pragma unroll
    for (int kh = 0; kh < 2; ++kh) {
      int8v a = __builtin_shufflevector(bw[kh], z4, 0, 1, 2, 3, 4, 5, 6, 7);
#pragma unroll
      for (int nt = 0; nt < 2; ++nt) {
        intx4 p0 = *(const intx4*)(act + mrd[nt][kh][0]);
        intx4 p1 = *(const intx4*)(act + mrd[nt][kh][1]);
        int8v mb = __builtin_shufflevector(p0, p1, 0, 1, 2, 3, 4, 5, 6, 7);
        hm[nt] = MFMA_F4F8(a, mb, hm[nt]);
      }
    }
    // republish h fp8 (x8 = hm * 2^-14)
#pragma unroll
    for (int nt = 0; nt < 2; ++nt)
      *(int*)(act + hrow[nt] + hwu) =
          pack_fp8(hm[nt][0] * 6.1035156e-5f, hm[nt][1] * 6.1035156e-5f,
                   hm[nt][2] * 6.1035156e-5f, hm[nt][3] * 6.1035156e-5f);
    __syncthreads();
  }

  // ---- epilogue: out[token][e] fp32 = hm / 131072, 16B stores
  const float inv = 1.0f / 131072.0f;
#pragma unroll
  for (int nt = 0; nt < 2; ++nt) {
    floatx4 v = hm[nt] * inv;
    *(floatx4*)&out[(size_t)(tokbase + nt * 16 + lm) * 128 + 16 * w2 + 4 * lq] = v;
  }
}

extern "C" void kernel_launch(void* const* d_in, const int* in_sizes, int n_in,
                              void* d_out, int out_size, void* d_ws, size_t ws_size,
                              hipStream_t stream) {
  const int* x = (const int*)d_in[0];
  const float* base_embed = (const float*)d_in[1];
  const float* W1 = (const float*)d_in[2];
  const float* W2 = (const float*)d_in[3];
  const int* membership = (const int*)d_in[4];
  float* out = (float*)d_out;

  unsigned* W1f = (unsigned*)d_ws;                 // 16 dom x 16KB = 256KB fp4
  unsigned* W2f = W1f + 16 * 4096;                 // 256KB (d=15 W1 prefetch
                                                   // overreads into this: benign)

  prep_weights<<<512, 256, 0, stream>>>(W1, W2, W1f, W2f);

  const int n_tokens = in_sizes[0];                // 32768
  domain_chain<<<n_tokens / 32, 512, 0, stream>>>(
      x, base_embed, membership, (const unsigned char*)W1f, (const unsigned char*)W2f, out);
}